// Round 9
// baseline (804.678 us; speedup 1.0000x reference)
//
#include <hip/hip_runtime.h>

// Problem constants: batch=4, seq=4096, dim=1024, fp32.
#define BATCH 4
#define SEQ   4096
#define DIM   1024
#define DIM4  256               // float4 lanes across dim
#define CH    16                // timesteps per chunk
#define NCH   (SEQ / CH)        // 256 chunks per batch
#define NBLK  (BATCH * NCH)     // 1024 blocks — all co-resident at 4 blocks/CU

typedef float vf4 __attribute__((ext_vector_type(4)));

__device__ __forceinline__ vf4 vfma4(vf4 a, vf4 h, vf4 b) {
    vf4 r;
    r.x = fmaf(a.x, h.x, b.x);
    r.y = fmaf(a.y, h.y, b.y);
    r.z = fmaf(a.z, h.z, b.z);
    r.w = fmaf(a.w, h.w, b.w);
    return r;
}

// flags: 0 = nothing, 1 = aggregate (P,Q) published, 2 = inclusive h_out published.
#define FLAG_NONE 0
#define FLAG_AGG  1
#define FLAG_INC  2

__global__ __launch_bounds__(1024) void zero_flags(int* flags) {
    flags[threadIdx.x] = FLAG_NONE;
}

// Single-pass selective scan with decoupled lookback (rocPRIM-style).
// Block g = (batch b = g>>8, chunk c = g&255). Chunks of a batch are scanned
// via AGG/INC publication; predecessors have smaller blockIdx (ordered dispatch,
// all 1024 blocks co-resident anyway).
__global__ __launch_bounds__(256, 4) void ssm_onepass(const vf4* __restrict__ gA,
                                                      const vf4* __restrict__ gB,
                                                      const vf4* __restrict__ gC,
                                                      vf4* __restrict__ gY,
                                                      int* __restrict__ flags,
                                                      vf4* __restrict__ aggP,
                                                      vf4* __restrict__ aggQ,
                                                      vf4* __restrict__ incH) {
    const int g  = blockIdx.x;
    const int c  = g & (NCH - 1);
    const int b  = g >> 8;
    const int d4 = threadIdx.x;

    const size_t base = ((size_t)b * SEQ + (size_t)c * CH) * DIM4 + d4;
    const size_t w    = (size_t)g * DIM4 + d4;

    // ---- Stage A: load A into registers (pinned — survives to the output pass),
    //      stream B through the local scan.
    vf4 av[CH];
#pragma unroll
    for (int t = 0; t < CH; ++t) av[t] = gA[base + (size_t)t * DIM4];
    asm volatile("" :
        "+v"(av[0]),  "+v"(av[1]),  "+v"(av[2]),  "+v"(av[3]),
        "+v"(av[4]),  "+v"(av[5]),  "+v"(av[6]),  "+v"(av[7]),
        "+v"(av[8]),  "+v"(av[9]),  "+v"(av[10]), "+v"(av[11]),
        "+v"(av[12]), "+v"(av[13]), "+v"(av[14]), "+v"(av[15]));

    vf4 p = av[0];
    vf4 q = gB[base];
#pragma unroll
    for (int t = 1; t < CH; ++t) {
        vf4 bb = gB[base + (size_t)t * DIM4];
        q = vfma4(av[t], q, bb);
        p = p * av[t];
    }

    // ---- Stage B: publish. c==0's aggregate IS its inclusive value (h_in = 0).
    if (c == 0) {
        incH[w] = q;
        __syncthreads();
        if (threadIdx.x == 0) {
            __threadfence();
            __hip_atomic_store(&flags[g], FLAG_INC, __ATOMIC_RELEASE, __HIP_MEMORY_SCOPE_AGENT);
        }
    } else {
        aggP[w] = p;
        aggQ[w] = q;
        __syncthreads();
        if (threadIdx.x == 0) {
            __threadfence();
            __hip_atomic_store(&flags[g], FLAG_AGG, __ATOMIC_RELEASE, __HIP_MEMORY_SCOPE_AGENT);
        }
    }

    // ---- Stage C: decoupled lookback — compose AGGs backward until an INC.
    vf4 h = (vf4)(0.f);   // carry-in for this chunk
    if (c > 0) {
        vf4 Pacc = (vf4)(1.f);
        vf4 Qacc = (vf4)(0.f);
        int j = g - 1;
        while (true) {
            int f;
            do {
                f = __hip_atomic_load(&flags[j], __ATOMIC_ACQUIRE, __HIP_MEMORY_SCOPE_AGENT);
                if (f == FLAG_NONE) __builtin_amdgcn_s_sleep(1);
            } while (f == FLAG_NONE);
            const size_t pj = (size_t)j * DIM4 + d4;
            if (f == FLAG_INC) {
                vf4 hj = incH[pj];
                h = vfma4(Pacc, hj, Qacc);   // h_in = M(h_out(j))
                break;
            } else {                          // FLAG_AGG: M <- M ∘ f_j
                vf4 Pj = aggP[pj];
                vf4 Qj = aggQ[pj];
                Qacc = vfma4(Pacc, Qj, Qacc);
                Pacc = Pacc * Pj;
                --j;
            }
        }
        // publish own inclusive: h_out = P*h_in + Q (p,q still in registers)
        incH[w] = vfma4(p, h, q);
        __syncthreads();
        if (threadIdx.x == 0) {
            __threadfence();
            __hip_atomic_store(&flags[g], FLAG_INC, __ATOMIC_RELEASE, __HIP_MEMORY_SCOPE_AGENT);
        }
    }

    // ---- Stage D: output pass — A from registers, B re-read (L3-hot),
    //      C nontemporal-in, Y nontemporal-out.
#pragma unroll
    for (int t = 0; t < CH; ++t) {
        vf4 bb = gB[base + (size_t)t * DIM4];
        vf4 cc = __builtin_nontemporal_load(&gC[base + (size_t)t * DIM4]);
        h = vfma4(av[t], h, bb);
        __builtin_nontemporal_store(cc * h, &gY[base + (size_t)t * DIM4]);
    }
}

extern "C" void kernel_launch(void* const* d_in, const int* in_sizes, int n_in,
                              void* d_out, int out_size, void* d_ws, size_t ws_size,
                              hipStream_t stream) {
    // setup_inputs order: x (unused), B, C, A — all fp32 [4, 4096, 1024]
    const vf4* B = (const vf4*)d_in[1];
    const vf4* C = (const vf4*)d_in[2];
    const vf4* A = (const vf4*)d_in[3];
    vf4* Y = (vf4*)d_out;

    // ws layout: flags (16 KB region), then aggP, aggQ, incH (4 MB each).
    char* ws = (char*)d_ws;
    int* flags = (int*)ws;
    vf4* aggP  = (vf4*)(ws + (16 << 10));
    vf4* aggQ  = aggP + (size_t)NBLK * DIM4;
    vf4* incH  = aggQ + (size_t)NBLK * DIM4;

    zero_flags<<<1, NBLK, 0, stream>>>(flags);
    ssm_onepass<<<NBLK, 256, 0, stream>>>(A, B, C, Y, flags, aggP, aggQ, incH);
}